// Round 5
// baseline (216.238 us; speedup 1.0000x reference)
//
#include <hip/hip_runtime.h>
#include <cstdint>

// ---------------- problem constants ----------------
static constexpr int B_  = 8192;
static constexpr int NW_ = 192;                 // NS + NV

typedef __attribute__((ext_vector_type(8))) _Float16 h8v;
typedef __attribute__((ext_vector_type(2))) _Float16 h2v;
typedef __attribute__((ext_vector_type(4))) float f4v;
typedef __attribute__((ext_vector_type(2))) float f2v;
typedef __attribute__((ext_vector_type(4))) unsigned u4v;

#define DI __device__ __forceinline__

DI h2v uh(unsigned u) { return __builtin_bit_cast(h2v, u); }
DI unsigned hu(h2v h) { return __builtin_bit_cast(unsigned, h); }
DI h2v hsplat(unsigned short bits) {
  _Float16 v = __builtin_bit_cast(_Float16, bits);
  h2v t; t.x = v; t.y = v; return t;
}
DI unsigned hpack(float lo, float hi) {
  h2v t; t.x = (_Float16)lo; t.y = (_Float16)hi;
  return __builtin_bit_cast(unsigned, t);
}
DI short f2h_bits(float f) { return __builtin_bit_cast(short, (_Float16)f); }

DI f4v mfma16h(h8v a, h8v b, f4v c) {
  return __builtin_amdgcn_mfma_f32_16x16x32_f16(a, b, c, 0, 0, 0);
}

// ---- block-symmetry tables (2 bits per block index) ----
static constexpr unsigned PK_BU0 = 606436u;   // {0,1,2,3,0,0,0,1,1,2}
static constexpr unsigned PK_BV0 = 1030628u;  // {0,1,2,3,1,2,3,2,3,3}
static constexpr unsigned PK_BU2 = 4u;        // {0,1,0}
static constexpr unsigned PK_BV2 = 20u;       // {0,1,1}
DI int tab2(unsigned pack, int blk) { return (int)((pack >> (2 * blk)) & 3u); }

// ---------------- prep: both weight tensors + accumulator zeroing, one launch ----------------
DI void prep_wsc_body(int g, const float* __restrict__ w000,
                      const float* __restrict__ w110, short* __restrict__ wf) {
  int lane = g & 63;
  int rest = g >> 6;
  int F = rest % 12;
  int s = rest / 12;
  int n = F * 16 + (lane & 15);
  int kk0 = (lane >> 4) << 3;
  const float s000 = 1.0f / (128.0f * 1.41421356237f);   // (1/N0) * inv_sqrt2
  const float s110 = 1.0f / (64.0f * 2.44948974968f);    // (1/(N1*sqrt3)) * inv_sqrt2
  short o[8];
  if (s < 320) {
    int blk = s >> 5, ik = s & 31;
    int bu = tab2(PK_BU0, blk), bv = tab2(PK_BV0, blk);
    int u = bu * 32 + ik;
#pragma unroll
    for (int j = 0; j < 8; ++j) {
      int v = bv * 32 + kk0 + j;
      float val = w000[(size_t)(u * 128 + v) * NW_ + n];
      if (bu != bv) val += w000[(size_t)(v * 128 + u) * NW_ + n];
      o[j] = f2h_bits(val * s000);
    }
  } else {
    int sp = s - 320;
    int blk = sp >> 5, ik = sp & 31;
    int bu = tab2(PK_BU2, blk), bv = tab2(PK_BV2, blk);
    int u = bu * 32 + ik;
#pragma unroll
    for (int j = 0; j < 8; ++j) {
      int v = bv * 32 + kk0 + j;
      float val = w110[(size_t)(u * 64 + v) * NW_ + n];
      if (bu != bv) val += w110[(size_t)(v * 64 + u) * NW_ + n];
      o[j] = f2h_bits(val * s110);
    }
  }
  *(h8v*)(wf + ((size_t)s * 12 + F) * 512 + lane * 8) = *(h8v*)o;
}

DI void prep_wvec_body(int g, const float* __restrict__ w011,
                       const float* __restrict__ w111, short* __restrict__ wf) {
  int lane = g & 63;
  int nf = (g >> 6) & 3;
  int s = g >> 8;
  int n = nf * 16 + (lane & 15);
  int kk0 = (lane >> 4) << 3;
  const float sv = 1.0f / 128.0f;
  short o[8];
  if (s < 256) {
#pragma unroll
    for (int j = 0; j < 8; ++j) {
      int k = s * 32 + kk0 + j;
      o[j] = f2h_bits(w011[(size_t)k * 64 + n] * sv);
    }
  } else {
    int sp = s - 256;
    int blk = sp >> 5, ik = sp & 31;
    int bu = tab2(PK_BU2, blk), bv = tab2(PK_BV2, blk);
    int u = bu * 32 + ik;
#pragma unroll
    for (int j = 0; j < 8; ++j) {
      int v = bv * 32 + kk0 + j;
      float val = w111[(size_t)(u * 64 + v) * 64 + n];
      if (bu != bv) val -= w111[(size_t)(v * 64 + u) * 64 + n];
      o[j] = f2h_bits(val * sv);
    }
  }
  *(h8v*)(wf + ((size_t)s * 4 + nf) * 512 + lane * 8) = *(h8v*)o;
}

// blocks [0,1248): wsc prep; [1248,1600): wvec prep; [1600,4672): zero 12.58 MB of acc
__global__ void prep_all(const float* __restrict__ w000, const float* __restrict__ w110,
                         const float* __restrict__ w011, const float* __restrict__ w111,
                         short* __restrict__ wsc, short* __restrict__ wve,
                         float* __restrict__ acc) {
  if (blockIdx.x < 1248) {
    prep_wsc_body(blockIdx.x * 256 + threadIdx.x, w000, w110, wsc);
  } else if (blockIdx.x < 1600) {
    prep_wvec_body((blockIdx.x - 1248) * 256 + threadIdx.x, w011, w111, wve);
  } else {
    int idx = (blockIdx.x - 1600) * 256 + threadIdx.x;  // 786432 threads x 16 B
    *(f4v*)(acc + (size_t)idx * 4) = f4v{0.f, 0.f, 0.f, 0.f};
  }
}

// ---------------- shared LDS staging: 32 rows of x, f16 ----------------
// 32-row tiles (R5): LDS/block = 32*136*2 + 32*200*2 = 21504 B -> 7 blocks/CU
// (vs 43008 B / 3 blocks/CU for 64-row tiles). Same total waves and per-wave
// work as R4; purely converts LDS headroom into resident waves (TLP).
#define X0H_STRIDE 136
#define X1_STRIDE  200

DI void stage_x32(const float* __restrict__ x, int b0,
                  unsigned short* X0H, unsigned short* X1) {
  const int t = threadIdx.x;            // 256 threads
  const int row = t >> 3, l8 = t & 7;   // 32 rows x 8 lanes
  const float* src = x + (size_t)(b0 + row) * 320;
  unsigned o[8];
#pragma unroll
  for (int j = 0; j < 4; ++j) {
    f4v v = *(const f4v*)(src + l8 * 16 + j * 4);
    o[2 * j]     = hpack(v.x, v.y);
    o[2 * j + 1] = hpack(v.z, v.w);
  }
  *(u4v*)(&X0H[row * X0H_STRIDE + l8 * 16])     = u4v{o[0], o[1], o[2], o[3]};
  *(u4v*)(&X0H[row * X0H_STRIDE + l8 * 16 + 8]) = u4v{o[4], o[5], o[6], o[7]};
  float buf[24];
#pragma unroll
  for (int j = 0; j < 12; ++j) {
    f2v v = *(const f2v*)(src + 128 + l8 * 24 + j * 2);
    buf[2 * j] = v.x; buf[2 * j + 1] = v.y;
  }
#pragma unroll
  for (int i = 0; i < 3; ++i) {
    u4v w;
#pragma unroll
    for (int e = 0; e < 4; ++e)
      w[e] = hpack(buf[(2 * e) * 3 + i], buf[(2 * e + 1) * 3 + i]);
    *(u4v*)(&X1[row * X1_STRIDE + i * 64 + l8 * 8]) = w;
  }
}

DI void loadB6(h8v* dst, const short* __restrict__ p) {
#pragma unroll
  for (int nf = 0; nf < 6; ++nf) dst[nf] = *(const h8v*)(p + nf * 512);
}
DI void loadB4(h8v* dst, const short* __restrict__ p) {
#pragma unroll
  for (int nf = 0; nf < 4; ++nf) dst[nf] = *(const h8v*)(p + nf * 512);
}

// ---------------- fused GEMM: sc path (bid&1==0) + vec path (bid&1==1) ----------------
// 256 threads / 4 waves / 32-row tile. Grid 2048 = 2 path x 256 mt x 4 kb.
// sc waves: nh2 x kh2 (mg gone); vec waves: mg2 x kh2. Per-wave work identical
// to R4. NOTE: keep VGPR_Count <= 64 — the HW allocation quantum halves
// occupancy above it (R2: 72 VGPR -> occ 31.5 -> 20.5, dur 133 -> 163 us).
__global__ __launch_bounds__(256, 8)
void gemm_fused(const float* __restrict__ x, const short* __restrict__ wsc,
                const short* __restrict__ wve,
                float* __restrict__ acc_sc, float* __restrict__ acc_ve) {
  __shared__ unsigned short X0H[32 * X0H_STRIDE];
  __shared__ unsigned short X1[32 * X1_STRIDE];
  const int path = blockIdx.x & 1;
  const int rest = blockIdx.x >> 1;     // 0..1023
  const int kb = rest & 3;
  const int b0 = (rest >> 2) * 32;

  stage_x32(x, b0, X0H, X1);
  __syncthreads();

  const int t0 = threadIdx.x;
  const int w = t0 >> 6, lane = t0 & 63;   // w in 0..3
  const int q = lane >> 4, r = lane & 15, q8 = q * 8;

  if (path == 0) {
    // ================= scalar path =================
    const int nh = w & 1, kh = w >> 1;
    const int c = kb * 2 + kh;          // chunk 0..7
    const unsigned short* x0A = &X0H[r * X0H_STRIDE];
    const unsigned short* x0B = &X0H[(r + 16) * X0H_STRIDE];
    const unsigned short* x1A = &X1[r * X1_STRIDE];
    const unsigned short* x1B = &X1[(r + 16) * X1_STRIDE];

    f4v acc[2][6];
#pragma unroll
    for (int f = 0; f < 2; ++f)
#pragma unroll
      for (int nf = 0; nf < 6; ++nf) acc[f][nf] = f4v{0.f, 0.f, 0.f, 0.f};

    // ---- region 1: x0 pair blocks, 40 steps ----
    {
      const short* wp = wsc + ((size_t)(c * 40) * 12 + nh * 6) * 512 + lane * 8;
      u4v pvA{}, pvB{};
      int bu32 = 0;
      h8v ba[6], bb[6];
      loadB6(ba, wp);
      auto step = [&](int t, const h8v* b) {
        const int s = c * 40 + t;
        const int ik = s & 31;
        if (t == 0 || ik == 0) {        // new 32x32 block: reload v-strip (wave-uniform)
          const int blk = s >> 5;
          const int bv32 = tab2(PK_BV0, blk) * 32;
          bu32 = tab2(PK_BU0, blk) * 32;
          pvA = *(const u4v*)(x0A + bv32 + q8);
          pvB = *(const u4v*)(x0B + bv32 + q8);
        }
        h2v xuA = hsplat(x0A[bu32 + ik]);
        h2v xuB = hsplat(x0B[bu32 + ik]);
        u4v pa0, pa1;
#pragma unroll
        for (int m = 0; m < 4; ++m) {
          pa0[m] = hu(uh(pvA[m]) * xuA);
          pa1[m] = hu(uh(pvB[m]) * xuB);
        }
        h8v a0 = __builtin_bit_cast(h8v, pa0);
        h8v a1 = __builtin_bit_cast(h8v, pa1);
        __builtin_amdgcn_s_setprio(1);
#pragma unroll
        for (int nf = 0; nf < 6; ++nf) {
          acc[0][nf] = mfma16h(a0, b[nf], acc[0][nf]);
          acc[1][nf] = mfma16h(a1, b[nf], acc[1][nf]);
        }
        __builtin_amdgcn_s_setprio(0);
      };
      for (int t2 = 0; t2 < 20; ++t2) {
        loadB6(bb, wp + 6144);          // prefetch odd step
        step(2 * t2, ba);
        if (t2 != 19) loadB6(ba, wp + 12288);  // prefetch next even step
        step(2 * t2 + 1, bb);
        wp += 12288;
      }
    }

    // ---- region 2: x1-dots pair blocks, 12 steps ----
    {
      const short* wp = wsc + ((size_t)(320 + c * 12) * 12 + nh * 6) * 512 + lane * 8;
      h8v ba[6], bb[6];
      loadB6(ba, wp);
      auto step = [&](int t, const h8v* b) {
        const int sp = c * 12 + t;
        const int blk = sp >> 5, ik = sp & 31;
        const int bu32 = tab2(PK_BU2, blk) * 32;
        const int bv32 = tab2(PK_BV2, blk) * 32;
        u4v pa0, pa1;
        {
          h2v us0 = hsplat(x1A[bu32 + ik]);
          h2v us1 = hsplat(x1A[64 + bu32 + ik]);
          h2v us2 = hsplat(x1A[128 + bu32 + ik]);
          u4v p0 = *(const u4v*)(x1A + bv32 + q8);
          u4v p1 = *(const u4v*)(x1A + 64 + bv32 + q8);
          u4v p2 = *(const u4v*)(x1A + 128 + bv32 + q8);
#pragma unroll
          for (int m = 0; m < 4; ++m) {
            h2v sm = uh(p0[m]) * us0;
            sm = sm + uh(p1[m]) * us1;
            sm = sm + uh(p2[m]) * us2;
            pa0[m] = hu(sm);
          }
        }
        {
          h2v us0 = hsplat(x1B[bu32 + ik]);
          h2v us1 = hsplat(x1B[64 + bu32 + ik]);
          h2v us2 = hsplat(x1B[128 + bu32 + ik]);
          u4v p0 = *(const u4v*)(x1B + bv32 + q8);
          u4v p1 = *(const u4v*)(x1B + 64 + bv32 + q8);
          u4v p2 = *(const u4v*)(x1B + 128 + bv32 + q8);
#pragma unroll
          for (int m = 0; m < 4; ++m) {
            h2v sm = uh(p0[m]) * us0;
            sm = sm + uh(p1[m]) * us1;
            sm = sm + uh(p2[m]) * us2;
            pa1[m] = hu(sm);
          }
        }
        h8v a0 = __builtin_bit_cast(h8v, pa0);
        h8v a1 = __builtin_bit_cast(h8v, pa1);
        __builtin_amdgcn_s_setprio(1);
#pragma unroll
        for (int nf = 0; nf < 6; ++nf) {
          acc[0][nf] = mfma16h(a0, b[nf], acc[0][nf]);
          acc[1][nf] = mfma16h(a1, b[nf], acc[1][nf]);
        }
        __builtin_amdgcn_s_setprio(0);
      };
      for (int t2 = 0; t2 < 6; ++t2) {
        loadB6(bb, wp + 6144);
        step(2 * t2, ba);
        if (t2 != 5) loadB6(ba, wp + 12288);
        step(2 * t2 + 1, bb);
        wp += 12288;
      }
    }

#pragma unroll
    for (int f = 0; f < 2; ++f)
#pragma unroll
      for (int nf = 0; nf < 6; ++nf) {
        int n = (nh * 6 + nf) * 16 + r;
#pragma unroll
        for (int reg = 0; reg < 4; ++reg) {
          int rowo = b0 + f * 16 + q * 4 + reg;
          atomicAdd(&acc_sc[(size_t)rowo * NW_ + n], acc[f][nf][reg]);
        }
      }
  } else {
    // ================= vector path =================
    const int mg = w & 1, kh = w >> 1;
    const int c = kb * 2 + kh;          // chunk 0..7
    const int row = mg * 16 + r;
    const unsigned short* x0r = &X0H[row * X0H_STRIDE];
    const unsigned short* x1r = &X1[row * X1_STRIDE];

    f4v acc[3][4];
#pragma unroll
    for (int ip = 0; ip < 3; ++ip)
#pragma unroll
      for (int nf = 0; nf < 4; ++nf) acc[ip][nf] = f4v{0.f, 0.f, 0.f, 0.f};

    // ---- region 1: v011 (x0 * x1[ip]), 32 steps (flattened g x j) ----
    {
      const int u0 = c * 16;
      const short* wp = wve + (size_t)(c * 32) * 2048 + lane * 8;
      h8v ba[4], bb[4];
      loadB4(ba, wp);
      auto vstep = [&](int st, const h8v* b) {
        const int g = st >> 1, j = st & 1;
        h2v xu2 = hsplat(x0r[u0 + g]);
        const int vb = j * 32 + q8;
        h8v a[3];
#pragma unroll
        for (int i = 0; i < 3; ++i) {
          u4v p = *(const u4v*)(x1r + i * 64 + vb);
          u4v pa;
#pragma unroll
          for (int m = 0; m < 4; ++m) pa[m] = hu(uh(p[m]) * xu2);
          a[i] = __builtin_bit_cast(h8v, pa);
        }
        __builtin_amdgcn_s_setprio(1);
#pragma unroll
        for (int ip = 0; ip < 3; ++ip)
#pragma unroll
          for (int nf = 0; nf < 4; ++nf)
            acc[ip][nf] = mfma16h(a[ip], b[nf], acc[ip][nf]);
        __builtin_amdgcn_s_setprio(0);
      };
      for (int t2 = 0; t2 < 16; ++t2) {
        loadB4(bb, wp + 2048);
        vstep(2 * t2, ba);
        if (t2 != 15) loadB4(ba, wp + 4096);
        vstep(2 * t2 + 1, bb);
        wp += 4096;
      }
    }

    // ---- region 2: v111 antisym pair blocks, 12 steps ----
    {
      const short* wp = wve + (size_t)(256 + c * 12) * 2048 + lane * 8;
      h8v ba[4], bb[4];
      loadB4(ba, wp);
      auto vstep = [&](int t, const h8v* b) {
        const int sp = c * 12 + t;
        const int blk = sp >> 5, ik = sp & 31;
        const int bu32 = tab2(PK_BU2, blk) * 32;
        const int bv32 = tab2(PK_BV2, blk) * 32;
        h2v us[3];
        u4v p[3];
#pragma unroll
        for (int i = 0; i < 3; ++i) {
          us[i] = hsplat(x1r[i * 64 + bu32 + ik]);
          p[i] = *(const u4v*)(x1r + i * 64 + bv32 + q8);
        }
        h8v a[3];
#pragma unroll
        for (int ip = 0; ip < 3; ++ip) {
          const int i1 = (ip + 1) % 3, i2 = (ip + 2) % 3;
          u4v pa;
#pragma unroll
          for (int m = 0; m < 4; ++m)
            pa[m] = hu(uh(p[i2][m]) * us[i1] - uh(p[i1][m]) * us[i2]);
          a[ip] = __builtin_bit_cast(h8v, pa);
        }
        __builtin_amdgcn_s_setprio(1);
#pragma unroll
        for (int ip = 0; ip < 3; ++ip)
#pragma unroll
          for (int nf = 0; nf < 4; ++nf)
            acc[ip][nf] = mfma16h(a[ip], b[nf], acc[ip][nf]);
        __builtin_amdgcn_s_setprio(0);
      };
      for (int t2 = 0; t2 < 6; ++t2) {
        loadB4(bb, wp + 2048);
        vstep(2 * t2, ba);
        if (t2 != 5) loadB4(ba, wp + 4096);
        vstep(2 * t2 + 1, bb);
        wp += 4096;
      }
    }

#pragma unroll
    for (int ip = 0; ip < 3; ++ip)
#pragma unroll
      for (int nf = 0; nf < 4; ++nf) {
        int n = nf * 16 + r;
#pragma unroll
        for (int reg = 0; reg < 4; ++reg) {
          int rowo = ip * B_ + b0 + mg * 16 + q * 4 + reg;
          atomicAdd(&acc_ve[(size_t)rowo * 64 + n], acc[ip][nf][reg]);
        }
      }
  }
}

// ---------------- epilogue: silu / sigmoid-gating, interleaved output ----------------
__global__ void epilogue(const float* __restrict__ sc, const float* __restrict__ ve,
                         float* __restrict__ out) {
  int t = blockIdx.x * blockDim.x + threadIdx.x;  // B*192 threads exactly
  int b = t / NW_, c = t % NW_;
  float v = sc[t];
  float sg = 1.0f / (1.0f + __expf(-v));
  if (c < 128) {
    out[(size_t)b * 320 + c] = v * sg;            // silu
  } else {
    int w = c - 128;
#pragma unroll
    for (int i = 0; i < 3; ++i) {
      float vv = ve[((size_t)i * B_ + b) * 64 + w];
      out[(size_t)b * 320 + 128 + w * 3 + i] = vv * sg;
    }
  }
}

// ---------------- launch ----------------
extern "C" void kernel_launch(void* const* d_in, const int* in_sizes, int n_in,
                              void* d_out, int out_size, void* d_ws, size_t ws_size,
                              hipStream_t stream) {
  const float* x    = (const float*)d_in[0];
  const float* w000 = (const float*)d_in[1];
  const float* w110 = (const float*)d_in[2];
  const float* w011 = (const float*)d_in[3];
  const float* w111 = (const float*)d_in[4];
  float* out = (float*)d_out;

  char* ws = (char*)d_ws;
  float* acc_sc = (float*)ws;                     // 8192*192*4  = 6,291,456 B
  float* acc_ve = (float*)(ws + 6291456);         // 3*8192*64*4 = 6,291,456 B
  short* wsc    = (short*)(ws + 12582912);        // 416*12*512*2 = 5,111,808 B
  short* wve    = (short*)(ws + 17694720);        // 352*4*512*2  = 1,441,792 B
  // total ws use: 19,136,512 B

  // prep_all also zeroes both accumulators (blocks 1600..4671) — no hipMemsetAsync
  prep_all  <<<4672, 256, 0, stream>>>(w000, w110, w011, w111, wsc, wve, acc_sc);
  gemm_fused<<<2048, 256, 0, stream>>>(x, wsc, wve, acc_sc, acc_ve);
  epilogue  <<<6144, 256, 0, stream>>>(acc_sc, acc_ve, out);
}

// Round 6
// 209.007 us; speedup vs baseline: 1.0346x; 1.0346x over previous
//
#include <hip/hip_runtime.h>
#include <cstdint>

// ---------------- problem constants ----------------
static constexpr int B_  = 8192;
static constexpr int NW_ = 192;                 // NS + NV

typedef __attribute__((ext_vector_type(8))) _Float16 h8v;
typedef __attribute__((ext_vector_type(2))) _Float16 h2v;
typedef __attribute__((ext_vector_type(4))) float f4v;
typedef __attribute__((ext_vector_type(2))) float f2v;
typedef __attribute__((ext_vector_type(4))) unsigned u4v;

#define DI __device__ __forceinline__

DI h2v uh(unsigned u) { return __builtin_bit_cast(h2v, u); }
DI unsigned hu(h2v h) { return __builtin_bit_cast(unsigned, h); }
DI h2v hsplat(unsigned short bits) {
  _Float16 v = __builtin_bit_cast(_Float16, bits);
  h2v t; t.x = v; t.y = v; return t;
}
DI unsigned hpack(float lo, float hi) {
  h2v t; t.x = (_Float16)lo; t.y = (_Float16)hi;
  return __builtin_bit_cast(unsigned, t);
}
DI short f2h_bits(float f) { return __builtin_bit_cast(short, (_Float16)f); }

DI f4v mfma16h(h8v a, h8v b, f4v c) {
  return __builtin_amdgcn_mfma_f32_16x16x32_f16(a, b, c, 0, 0, 0);
}

// ---- block-symmetry tables (2 bits per block index) ----
static constexpr unsigned PK_BU0 = 606436u;   // {0,1,2,3,0,0,0,1,1,2}
static constexpr unsigned PK_BV0 = 1030628u;  // {0,1,2,3,1,2,3,2,3,3}
static constexpr unsigned PK_BU2 = 4u;        // {0,1,0}
static constexpr unsigned PK_BV2 = 20u;       // {0,1,1}
DI int tab2(unsigned pack, int blk) { return (int)((pack >> (2 * blk)) & 3u); }

// ---------------- prep: both weight tensors + accumulator zeroing, one launch ----------------
DI void prep_wsc_body(int g, const float* __restrict__ w000,
                      const float* __restrict__ w110, short* __restrict__ wf) {
  int lane = g & 63;
  int rest = g >> 6;
  int F = rest % 12;
  int s = rest / 12;
  int n = F * 16 + (lane & 15);
  int kk0 = (lane >> 4) << 3;
  const float s000 = 1.0f / (128.0f * 1.41421356237f);   // (1/N0) * inv_sqrt2
  const float s110 = 1.0f / (64.0f * 2.44948974968f);    // (1/(N1*sqrt3)) * inv_sqrt2
  short o[8];
  if (s < 320) {
    int blk = s >> 5, ik = s & 31;
    int bu = tab2(PK_BU0, blk), bv = tab2(PK_BV0, blk);
    int u = bu * 32 + ik;
#pragma unroll
    for (int j = 0; j < 8; ++j) {
      int v = bv * 32 + kk0 + j;
      float val = w000[(size_t)(u * 128 + v) * NW_ + n];
      if (bu != bv) val += w000[(size_t)(v * 128 + u) * NW_ + n];
      o[j] = f2h_bits(val * s000);
    }
  } else {
    int sp = s - 320;
    int blk = sp >> 5, ik = sp & 31;
    int bu = tab2(PK_BU2, blk), bv = tab2(PK_BV2, blk);
    int u = bu * 32 + ik;
#pragma unroll
    for (int j = 0; j < 8; ++j) {
      int v = bv * 32 + kk0 + j;
      float val = w110[(size_t)(u * 64 + v) * NW_ + n];
      if (bu != bv) val += w110[(size_t)(v * 64 + u) * NW_ + n];
      o[j] = f2h_bits(val * s110);
    }
  }
  *(h8v*)(wf + ((size_t)s * 12 + F) * 512 + lane * 8) = *(h8v*)o;
}

DI void prep_wvec_body(int g, const float* __restrict__ w011,
                       const float* __restrict__ w111, short* __restrict__ wf) {
  int lane = g & 63;
  int nf = (g >> 6) & 3;
  int s = g >> 8;
  int n = nf * 16 + (lane & 15);
  int kk0 = (lane >> 4) << 3;
  const float sv = 1.0f / 128.0f;
  short o[8];
  if (s < 256) {
#pragma unroll
    for (int j = 0; j < 8; ++j) {
      int k = s * 32 + kk0 + j;
      o[j] = f2h_bits(w011[(size_t)k * 64 + n] * sv);
    }
  } else {
    int sp = s - 256;
    int blk = sp >> 5, ik = sp & 31;
    int bu = tab2(PK_BU2, blk), bv = tab2(PK_BV2, blk);
    int u = bu * 32 + ik;
#pragma unroll
    for (int j = 0; j < 8; ++j) {
      int v = bv * 32 + kk0 + j;
      float val = w111[(size_t)(u * 64 + v) * 64 + n];
      if (bu != bv) val -= w111[(size_t)(v * 64 + u) * 64 + n];
      o[j] = f2h_bits(val * sv);
    }
  }
  *(h8v*)(wf + ((size_t)s * 4 + nf) * 512 + lane * 8) = *(h8v*)o;
}

// blocks [0,1248): wsc prep; [1248,1600): wvec prep; [1600,4672): zero 12.58 MB of acc
__global__ void prep_all(const float* __restrict__ w000, const float* __restrict__ w110,
                         const float* __restrict__ w011, const float* __restrict__ w111,
                         short* __restrict__ wsc, short* __restrict__ wve,
                         float* __restrict__ acc) {
  if (blockIdx.x < 1248) {
    prep_wsc_body(blockIdx.x * 256 + threadIdx.x, w000, w110, wsc);
  } else if (blockIdx.x < 1600) {
    prep_wvec_body((blockIdx.x - 1248) * 256 + threadIdx.x, w011, w111, wve);
  } else {
    int idx = (blockIdx.x - 1600) * 256 + threadIdx.x;  // 786432 threads x 16 B
    *(f4v*)(acc + (size_t)idx * 4) = f4v{0.f, 0.f, 0.f, 0.f};
  }
}

// ---------------- shared LDS staging: 64 rows of x, f16, 256 threads (2 passes) ----------------
#define X0H_STRIDE 136
#define X1_STRIDE  200

DI void stage_x64(const float* __restrict__ x, int b0,
                  unsigned short* X0H, unsigned short* X1) {
  const int t = threadIdx.x;            // 256 threads
#pragma unroll
  for (int pass = 0; pass < 2; ++pass) {
    const int row = pass * 32 + (t >> 3), l8 = t & 7;
    const float* src = x + (size_t)(b0 + row) * 320;
    unsigned o[8];
#pragma unroll
    for (int j = 0; j < 4; ++j) {
      f4v v = *(const f4v*)(src + l8 * 16 + j * 4);
      o[2 * j]     = hpack(v.x, v.y);
      o[2 * j + 1] = hpack(v.z, v.w);
    }
    *(u4v*)(&X0H[row * X0H_STRIDE + l8 * 16])     = u4v{o[0], o[1], o[2], o[3]};
    *(u4v*)(&X0H[row * X0H_STRIDE + l8 * 16 + 8]) = u4v{o[4], o[5], o[6], o[7]};
    float buf[24];
#pragma unroll
    for (int j = 0; j < 12; ++j) {
      f2v v = *(const f2v*)(src + 128 + l8 * 24 + j * 2);
      buf[2 * j] = v.x; buf[2 * j + 1] = v.y;
    }
#pragma unroll
    for (int i = 0; i < 3; ++i) {
      u4v w;
#pragma unroll
      for (int e = 0; e < 4; ++e)
        w[e] = hpack(buf[(2 * e) * 3 + i], buf[(2 * e + 1) * 3 + i]);
      *(u4v*)(&X1[row * X1_STRIDE + i * 64 + l8 * 8]) = w;
    }
  }
}

DI void loadB6(h8v* dst, const short* __restrict__ p) {
#pragma unroll
  for (int nf = 0; nf < 6; ++nf) dst[nf] = *(const h8v*)(p + nf * 512);
}
DI void loadB4(h8v* dst, const short* __restrict__ p) {
#pragma unroll
  for (int nf = 0; nf < 4; ++nf) dst[nf] = *(const h8v*)(p + nf * 512);
}

// ---------------- fused GEMM: sc path (bid&1==0) + vec path (bid&1==1) ----------------
// R6: 256 threads / 4 waves over a 64-row X tile. Each wave now carries FOUR
// 16-row A-fragments (f=0..3 sc; fg+ff vec), amortizing every B-frag load over
// 24 MFMAs instead of 12 -> B bytes/MFMA 512 -> 256 (sc) / 170 (vec); total
// L2 B-traffic halves. acc = 96 AGPR + ~105 VGPR => 2 waves/SIMD (unified-file
// quantum: waves/SIMD = 8/4/2 at total <=64/<=128/<=256 regs — R2/R4/R5 data).
__global__ __launch_bounds__(256, 2)
void gemm_fused(const float* __restrict__ x, const short* __restrict__ wsc,
                const short* __restrict__ wve,
                float* __restrict__ acc_sc, float* __restrict__ acc_ve) {
  __shared__ unsigned short X0H[64 * X0H_STRIDE];
  __shared__ unsigned short X1[64 * X1_STRIDE];
  const int path = blockIdx.x & 1;
  const int rest = blockIdx.x >> 1;     // 0..511
  const int kb = rest & 3;
  const int b0 = (rest >> 2) * 64;

  stage_x64(x, b0, X0H, X1);
  __syncthreads();

  const int t0 = threadIdx.x;
  const int w = t0 >> 6, lane = t0 & 63;   // w in 0..3
  const int q = lane >> 4, r = lane & 15, q8 = q * 8;

  if (path == 0) {
    // ================= scalar path =================
    const int nh = w & 1, kh = w >> 1;
    const int c = kb * 2 + kh;          // chunk 0..7
    const unsigned short* x0f[4];
    const unsigned short* x1f[4];
#pragma unroll
    for (int f = 0; f < 4; ++f) {
      x0f[f] = &X0H[(f * 16 + r) * X0H_STRIDE];
      x1f[f] = &X1[(f * 16 + r) * X1_STRIDE];
    }

    f4v acc[4][6];
#pragma unroll
    for (int f = 0; f < 4; ++f)
#pragma unroll
      for (int nf = 0; nf < 6; ++nf) acc[f][nf] = f4v{0.f, 0.f, 0.f, 0.f};

    // ---- region 1: x0 pair blocks, 40 steps ----
    {
      const short* wp = wsc + ((size_t)(c * 40) * 12 + nh * 6) * 512 + lane * 8;
      u4v pv[4];
#pragma unroll
      for (int f = 0; f < 4; ++f) pv[f] = u4v{0, 0, 0, 0};
      int bu32 = 0;
      h8v ba[6], bb[6];
      loadB6(ba, wp);
      auto step = [&](int t, const h8v* b) {
        const int s = c * 40 + t;
        const int ik = s & 31;
        if (t == 0 || ik == 0) {        // new 32x32 block: reload v-strips (wave-uniform)
          const int blk = s >> 5;
          const int bv32 = tab2(PK_BV0, blk) * 32;
          bu32 = tab2(PK_BU0, blk) * 32;
#pragma unroll
          for (int f = 0; f < 4; ++f) pv[f] = *(const u4v*)(x0f[f] + bv32 + q8);
        }
        h8v a[4];
#pragma unroll
        for (int f = 0; f < 4; ++f) {
          h2v xu = hsplat(x0f[f][bu32 + ik]);
          u4v pa;
#pragma unroll
          for (int m = 0; m < 4; ++m) pa[m] = hu(uh(pv[f][m]) * xu);
          a[f] = __builtin_bit_cast(h8v, pa);
        }
        __builtin_amdgcn_s_setprio(1);
#pragma unroll
        for (int nf = 0; nf < 6; ++nf)
#pragma unroll
          for (int f = 0; f < 4; ++f)
            acc[f][nf] = mfma16h(a[f], b[nf], acc[f][nf]);
        __builtin_amdgcn_s_setprio(0);
      };
      for (int t2 = 0; t2 < 20; ++t2) {
        loadB6(bb, wp + 6144);          // prefetch odd step
        step(2 * t2, ba);
        if (t2 != 19) loadB6(ba, wp + 12288);  // prefetch next even step
        step(2 * t2 + 1, bb);
        wp += 12288;
      }
    }

    // ---- region 2: x1-dots pair blocks, 12 steps ----
    {
      const short* wp = wsc + ((size_t)(320 + c * 12) * 12 + nh * 6) * 512 + lane * 8;
      h8v ba[6], bb[6];
      loadB6(ba, wp);
      auto step = [&](int t, const h8v* b) {
        const int sp = c * 12 + t;
        const int blk = sp >> 5, ik = sp & 31;
        const int bu32 = tab2(PK_BU2, blk) * 32;
        const int bv32 = tab2(PK_BV2, blk) * 32;
        h8v a[4];
#pragma unroll
        for (int f = 0; f < 4; ++f) {
          h2v us0 = hsplat(x1f[f][bu32 + ik]);
          h2v us1 = hsplat(x1f[f][64 + bu32 + ik]);
          h2v us2 = hsplat(x1f[f][128 + bu32 + ik]);
          u4v p0 = *(const u4v*)(x1f[f] + bv32 + q8);
          u4v p1 = *(const u4v*)(x1f[f] + 64 + bv32 + q8);
          u4v p2 = *(const u4v*)(x1f[f] + 128 + bv32 + q8);
          u4v pa;
#pragma unroll
          for (int m = 0; m < 4; ++m) {
            h2v sm = uh(p0[m]) * us0;
            sm = sm + uh(p1[m]) * us1;
            sm = sm + uh(p2[m]) * us2;
            pa[m] = hu(sm);
          }
          a[f] = __builtin_bit_cast(h8v, pa);
        }
        __builtin_amdgcn_s_setprio(1);
#pragma unroll
        for (int nf = 0; nf < 6; ++nf)
#pragma unroll
          for (int f = 0; f < 4; ++f)
            acc[f][nf] = mfma16h(a[f], b[nf], acc[f][nf]);
        __builtin_amdgcn_s_setprio(0);
      };
      for (int t2 = 0; t2 < 6; ++t2) {
        loadB6(bb, wp + 6144);
        step(2 * t2, ba);
        if (t2 != 5) loadB6(ba, wp + 12288);
        step(2 * t2 + 1, bb);
        wp += 12288;
      }
    }

#pragma unroll
    for (int f = 0; f < 4; ++f)
#pragma unroll
      for (int nf = 0; nf < 6; ++nf) {
        int n = (nh * 6 + nf) * 16 + r;
#pragma unroll
        for (int reg = 0; reg < 4; ++reg) {
          int rowo = b0 + f * 16 + q * 4 + reg;
          atomicAdd(&acc_sc[(size_t)rowo * NW_ + n], acc[f][nf][reg]);
        }
      }
  } else {
    // ================= vector path =================
    const int fg = w & 1, kh = w >> 1;
    const int c = kb * 2 + kh;          // chunk 0..7
    const unsigned short* x0r[2];
    const unsigned short* x1r[2];
#pragma unroll
    for (int ff = 0; ff < 2; ++ff) {
      int row = fg * 32 + ff * 16 + r;
      x0r[ff] = &X0H[row * X0H_STRIDE];
      x1r[ff] = &X1[row * X1_STRIDE];
    }

    f4v acc[2][3][4];
#pragma unroll
    for (int ff = 0; ff < 2; ++ff)
#pragma unroll
      for (int ip = 0; ip < 3; ++ip)
#pragma unroll
        for (int nf = 0; nf < 4; ++nf) acc[ff][ip][nf] = f4v{0.f, 0.f, 0.f, 0.f};

    // ---- region 1: v011 (x0 * x1[ip]), 32 steps (flattened g x j) ----
    {
      const int u0 = c * 16;
      const short* wp = wve + (size_t)(c * 32) * 2048 + lane * 8;
      h8v ba[4], bb[4];
      loadB4(ba, wp);
      auto vstep = [&](int st, const h8v* b) {
        const int g = st >> 1, j = st & 1;
        const int vb = j * 32 + q8;
        h8v a[2][3];
#pragma unroll
        for (int ff = 0; ff < 2; ++ff) {
          h2v xu2 = hsplat(x0r[ff][u0 + g]);
#pragma unroll
          for (int i = 0; i < 3; ++i) {
            u4v p = *(const u4v*)(x1r[ff] + i * 64 + vb);
            u4v pa;
#pragma unroll
            for (int m = 0; m < 4; ++m) pa[m] = hu(uh(p[m]) * xu2);
            a[ff][i] = __builtin_bit_cast(h8v, pa);
          }
        }
        __builtin_amdgcn_s_setprio(1);
#pragma unroll
        for (int ip = 0; ip < 3; ++ip)
#pragma unroll
          for (int nf = 0; nf < 4; ++nf)
#pragma unroll
            for (int ff = 0; ff < 2; ++ff)
              acc[ff][ip][nf] = mfma16h(a[ff][ip], b[nf], acc[ff][ip][nf]);
        __builtin_amdgcn_s_setprio(0);
      };
      for (int t2 = 0; t2 < 16; ++t2) {
        loadB4(bb, wp + 2048);
        vstep(2 * t2, ba);
        if (t2 != 15) loadB4(ba, wp + 4096);
        vstep(2 * t2 + 1, bb);
        wp += 4096;
      }
    }

    // ---- region 2: v111 antisym pair blocks, 12 steps ----
    {
      const short* wp = wve + (size_t)(256 + c * 12) * 2048 + lane * 8;
      h8v ba[4], bb[4];
      loadB4(ba, wp);
      auto vstep = [&](int t, const h8v* b) {
        const int sp = c * 12 + t;
        const int blk = sp >> 5, ik = sp & 31;
        const int bu32 = tab2(PK_BU2, blk) * 32;
        const int bv32 = tab2(PK_BV2, blk) * 32;
        h8v a[2][3];
#pragma unroll
        for (int ff = 0; ff < 2; ++ff) {
          h2v us[3];
          u4v p[3];
#pragma unroll
          for (int i = 0; i < 3; ++i) {
            us[i] = hsplat(x1r[ff][i * 64 + bu32 + ik]);
            p[i] = *(const u4v*)(x1r[ff] + i * 64 + bv32 + q8);
          }
#pragma unroll
          for (int ip = 0; ip < 3; ++ip) {
            const int i1 = (ip + 1) % 3, i2 = (ip + 2) % 3;
            u4v pa;
#pragma unroll
            for (int m = 0; m < 4; ++m)
              pa[m] = hu(uh(p[i2][m]) * us[i1] - uh(p[i1][m]) * us[i2]);
            a[ff][ip] = __builtin_bit_cast(h8v, pa);
          }
        }
        __builtin_amdgcn_s_setprio(1);
#pragma unroll
        for (int ip = 0; ip < 3; ++ip)
#pragma unroll
          for (int nf = 0; nf < 4; ++nf)
#pragma unroll
            for (int ff = 0; ff < 2; ++ff)
              acc[ff][ip][nf] = mfma16h(a[ff][ip], b[nf], acc[ff][ip][nf]);
        __builtin_amdgcn_s_setprio(0);
      };
      for (int t2 = 0; t2 < 6; ++t2) {
        loadB4(bb, wp + 2048);
        vstep(2 * t2, ba);
        if (t2 != 5) loadB4(ba, wp + 4096);
        vstep(2 * t2 + 1, bb);
        wp += 4096;
      }
    }

#pragma unroll
    for (int ff = 0; ff < 2; ++ff)
#pragma unroll
      for (int ip = 0; ip < 3; ++ip)
#pragma unroll
        for (int nf = 0; nf < 4; ++nf) {
          int n = nf * 16 + r;
#pragma unroll
          for (int reg = 0; reg < 4; ++reg) {
            int rowo = ip * B_ + b0 + fg * 32 + ff * 16 + q * 4 + reg;
            atomicAdd(&acc_ve[(size_t)rowo * 64 + n], acc[ff][ip][nf][reg]);
          }
        }
  }
}

// ---------------- epilogue: silu / sigmoid-gating, interleaved output ----------------
__global__ void epilogue(const float* __restrict__ sc, const float* __restrict__ ve,
                         float* __restrict__ out) {
  int t = blockIdx.x * blockDim.x + threadIdx.x;  // B*192 threads exactly
  int b = t / NW_, c = t % NW_;
  float v = sc[t];
  float sg = 1.0f / (1.0f + __expf(-v));
  if (c < 128) {
    out[(size_t)b * 320 + c] = v * sg;            // silu
  } else {
    int w = c - 128;
#pragma unroll
    for (int i = 0; i < 3; ++i) {
      float vv = ve[((size_t)i * B_ + b) * 64 + w];
      out[(size_t)b * 320 + 128 + w * 3 + i] = vv * sg;
    }
  }
}

// ---------------- launch ----------------
extern "C" void kernel_launch(void* const* d_in, const int* in_sizes, int n_in,
                              void* d_out, int out_size, void* d_ws, size_t ws_size,
                              hipStream_t stream) {
  const float* x    = (const float*)d_in[0];
  const float* w000 = (const float*)d_in[1];
  const float* w110 = (const float*)d_in[2];
  const float* w011 = (const float*)d_in[3];
  const float* w111 = (const float*)d_in[4];
  float* out = (float*)d_out;

  char* ws = (char*)d_ws;
  float* acc_sc = (float*)ws;                     // 8192*192*4  = 6,291,456 B
  float* acc_ve = (float*)(ws + 6291456);         // 3*8192*64*4 = 6,291,456 B
  short* wsc    = (short*)(ws + 12582912);        // 416*12*512*2 = 5,111,808 B
  short* wve    = (short*)(ws + 17694720);        // 352*4*512*2  = 1,441,792 B
  // total ws use: 19,136,512 B

  // prep_all also zeroes both accumulators (blocks 1600..4671) — no hipMemsetAsync
  prep_all  <<<4672, 256, 0, stream>>>(w000, w110, w011, w111, wsc, wve, acc_sc);
  gemm_fused<<<1024, 256, 0, stream>>>(x, wsc, wve, acc_sc, acc_ve);
  epilogue  <<<6144, 256, 0, stream>>>(acc_sc, acc_ve, out);
}